// Round 4
// baseline (500.189 us; speedup 1.0000x reference)
//
#include <hip/hip_runtime.h>
#include <hip/hip_bf16.h>

// Problem constants
#define NB    8
#define SQN   2048
#define SKN   4096
#define DDIM  512
#define DVDIM 256
#define NROWS (NB*SQN)      // 16384

typedef __attribute__((ext_vector_type(8))) short bf16x8;   // 8 bf16 = 4 VGPRs (MFMA A/B frag)
typedef __attribute__((ext_vector_type(4))) short bf16x4;
typedef __attribute__((ext_vector_type(4))) float f32x4;    // MFMA C/D frag

// fp32 -> bf16 round-to-nearest-even, bit pattern as short
__device__ __forceinline__ short f2bf(float f) {
    unsigned u = __float_as_uint(f);
    return (short)((u + 0x7FFFu + ((u >> 16) & 1u)) >> 16);
}

// async global->LDS, 16B per lane; LDS dst = wave-uniform base + lane*16,
// global src is a per-lane address (this is how we swizzle on the read side)
__device__ __forceinline__ void gload_lds16(const void* g, void* l) {
    __builtin_amdgcn_global_load_lds(
        (const __attribute__((address_space(1))) unsigned int*)g,
        (__attribute__((address_space(3))) unsigned int*)l, 16, 0, 0);
}

// ---------------------------------------------------------------------------
// Generic NT GEMM: C[m][n] = sum_k A[m][k]*B[n][k], A:MxK f32, B:NxK f32,
// C natural row-major bf16 (coalesced stores; swizzle happens at attn's
// read-side staging). Tiles 64x64, block=256 (4 waves x 16 rows), Kc=128.
// grid = (M/64, N/64)
// ---------------------------------------------------------------------------
__global__ __launch_bounds__(256, 2) void gemm_nt_f32_bf16(
    const float* __restrict__ A, const float* __restrict__ Bm,
    unsigned short* __restrict__ C, int M, int N, int K)
{
    __shared__ short sA[64*128];   // 16 KB
    __shared__ short sB[64*128];   // 16 KB
    const int tid  = threadIdx.x;
    const int wave = tid >> 6;
    const int lane = tid & 63;
    const int quad = lane >> 4;
    const int l15  = lane & 15;
    const int m0 = blockIdx.x * 64;
    const int n0 = blockIdx.y * 64;

    f32x4 acc[4];
    #pragma unroll
    for (int n = 0; n < 4; ++n) { acc[n][0]=0.f; acc[n][1]=0.f; acc[n][2]=0.f; acc[n][3]=0.f; }

    for (int kc = 0; kc < K; kc += 128) {
        __syncthreads();
        #pragma unroll
        for (int it = 0; it < 8; ++it) {
            int f = it*1024 + tid*4;          // element index in 64x128 tile
            int row = f >> 7, col = f & 127;
            float4 av = *(const float4*)(A + (size_t)(m0+row)*K + kc + col);
            bf16x4 a4; a4[0]=f2bf(av.x); a4[1]=f2bf(av.y); a4[2]=f2bf(av.z); a4[3]=f2bf(av.w);
            *(bf16x4*)(sA + f) = a4;
            float4 bv = *(const float4*)(Bm + (size_t)(n0+row)*K + kc + col);
            bf16x4 b4; b4[0]=f2bf(bv.x); b4[1]=f2bf(bv.y); b4[2]=f2bf(bv.z); b4[3]=f2bf(bv.w);
            *(bf16x4*)(sB + f) = b4;
        }
        __syncthreads();
        #pragma unroll
        for (int t = 0; t < 4; ++t) {
            bf16x8 af = *(const bf16x8*)(sA + (wave*16 + l15)*128 + t*32 + quad*8);
            #pragma unroll
            for (int n = 0; n < 4; ++n) {
                bf16x8 bfr = *(const bf16x8*)(sB + (n*16 + l15)*128 + t*32 + quad*8);
                acc[n] = __builtin_amdgcn_mfma_f32_16x16x32_bf16(af, bfr, acc[n], 0, 0, 0);
            }
        }
    }
    // epilogue: D row=quad*4+r, col=l15; natural row-major stores
    #pragma unroll
    for (int n = 0; n < 4; ++n)
        #pragma unroll
        for (int r = 0; r < 4; ++r) {
            int m  = m0 + wave*16 + quad*4 + r;
            int nn = n0 + n*16 + l15;
            C[(size_t)m*N + nn] = (unsigned short)f2bf(acc[n][r]);
        }
}

// ---------------------------------------------------------------------------
// Fused attention: grid = (NROWS/64, nsplit), block = 256 (4 waves x 16 rows).
//  R2-proven body + (a) read-side swizzle staging from natural-layout KV,
//  (b) sP aliased into sK (LDS 48 KB -> 3 blocks/CU), (c) launch_bounds(256,3).
//  Per j-iter: 4 K-chunks (64 keys x 128 d) staged+QK'd, then softmax,
//  P into sK-alias (after a barrier), PV from sV.
// ---------------------------------------------------------------------------
__global__ __launch_bounds__(256, 3) void attn_fused(
    const float* __restrict__ X,            // [16384][512] fp32
    const unsigned short* __restrict__ Kb,  // key bf16 [4096][512] natural
    const unsigned short* __restrict__ Vt,  // V^T bf16 [256][4096] natural
    float* __restrict__ Opart,              // [nsplit][16384][256]
    float* __restrict__ Mpart,              // [nsplit][16384]
    float* __restrict__ Lpart,              // [nsplit][16384]
    int nj)                                 // key-blocks per split
{
    __shared__ short sK[8192];      // 16 KB: K chunk, 64 keys x 128 d (swizzled)
    __shared__ short sV[16384];     // 32 KB: V^T 256 x 64 keys (swizzled)
    // sP aliases first 8 KB of sK (P written only after all QK reads done)
    const int tid  = threadIdx.x;
    const int wave = tid >> 6;
    const int lane = tid & 63;
    const int quad = lane >> 4;
    const int l15  = lane & 15;
    const int l7   = lane & 7;
    const int split = blockIdx.y;
    const int q0   = blockIdx.x * 64;
    const int sb0  = split * nj;
    const float scale = 0.04419417382415922f;  // 1/sqrt(512)

    // Q fragments (scale folded): A[m=l15][k=quad*8+j], 16 k-steps (64 VGPRs)
    bf16x8 qf[16];
    {
        const float* xrow = X + (size_t)(q0 + wave*16 + l15) * DDIM;
        #pragma unroll
        for (int t = 0; t < 16; ++t) {
            float4 a = *(const float4*)(xrow + t*32 + quad*8);
            float4 b = *(const float4*)(xrow + t*32 + quad*8 + 4);
            bf16x8 q;
            q[0]=f2bf(a.x*scale); q[1]=f2bf(a.y*scale); q[2]=f2bf(a.z*scale); q[3]=f2bf(a.w*scale);
            q[4]=f2bf(b.x*scale); q[5]=f2bf(b.y*scale); q[6]=f2bf(b.z*scale); q[7]=f2bf(b.w*scale);
            qf[t] = q;
        }
    }

    f32x4 o[16];
    #pragma unroll
    for (int i = 0; i < 16; ++i) { o[i][0]=0.f; o[i][1]=0.f; o[i][2]=0.f; o[i][3]=0.f; }
    float m_r[4] = {-1e30f,-1e30f,-1e30f,-1e30f};
    float l_r[4] = {0.f,0.f,0.f,0.f};
    short* sPw = sK + wave*1024;    // 16 rows x 64 keys, wave-private alias

    // wave-uniform swizzle constants for read-side staging
    const int wq = wave*4 + quad;   // K-stage row phase (= row & 15)

    for (int j = 0; j < nj; ++j) {
        const int sk0 = (sb0 + j) * 64;
        f32x4 s[4];
        #pragma unroll
        for (int n = 0; n < 4; ++n) { s[n][0]=0.f; s[n][1]=0.f; s[n][2]=0.f; s[n][3]=0.f; }

        #pragma unroll
        for (int c = 0; c < 4; ++c) {
            __syncthreads();   // (A) prior consumers of sK/sV/P are done
            if (c == 0) {
                // stage V^T tile 256x64 from natural layout, swizzled src:
                // dest chunk L=it*256+wave*64+lane -> dv=it*32+wave*8+(lane>>3),
                // slot=lane&7 holds key-chunk (l7 ^ (lane>>3))
                const unsigned short* vsrc = Vt + sk0
                    + (size_t)(wave*8 + (lane>>3))*SKN + ((l7 ^ (lane>>3)) << 3);
                char* vdst = (char*)sV + wave*1024;
                #pragma unroll
                for (int it = 0; it < 8; ++it)
                    gload_lds16(vsrc + (size_t)it*32*SKN, vdst + it*4096);
            }
            // stage K chunk 64x128 from natural layout, swizzled src:
            // dest row = it*16 + wave*4 + quad, slot=l15 holds d-chunk (l15 ^ wq)
            const unsigned short* ksrc = Kb + (size_t)(sk0 + wq)*DDIM
                + c*128 + ((l15 ^ wq) << 3);
            char* kdst = (char*)sK + wave*1024;
            #pragma unroll
            for (int it = 0; it < 4; ++it)
                gload_lds16(ksrc + (size_t)it*16*DDIM, kdst + it*4096);
            __syncthreads();   // (B) staged data visible
            // S += Q_chunk * K_chunk^T (swizzled B-frag reads, conflict-free)
            #pragma unroll
            for (int t = 0; t < 4; ++t) {
                bf16x8 af = qf[c*4 + t];
                #pragma unroll
                for (int n = 0; n < 4; ++n) {
                    bf16x8 bfr = *(const bf16x8*)(sK + (n*16 + l15)*128
                                                  + (((t*4 + quad) ^ l15) << 3));
                    s[n] = __builtin_amdgcn_mfma_f32_16x16x32_bf16(af, bfr, s[n], 0, 0, 0);
                }
            }
        }
        __syncthreads();       // (C) all QK reads of sK done -> P may overwrite

        // ---- online softmax (rows = quad*4+r), P written inline to sP ----
        float alpha[4];
        int need_rescale = 0;
        #pragma unroll
        for (int r = 0; r < 4; ++r) {
            float v = fmaxf(fmaxf(s[0][r], s[1][r]), fmaxf(s[2][r], s[3][r]));
            v = fmaxf(v, __shfl_xor(v, 1));
            v = fmaxf(v, __shfl_xor(v, 2));
            v = fmaxf(v, __shfl_xor(v, 4));
            v = fmaxf(v, __shfl_xor(v, 8));
            float mn = fmaxf(m_r[r], v);
            float a  = __expf(m_r[r] - mn);
            alpha[r] = a;
            need_rescale |= (a < 1.0f);
            m_r[r] = mn;
            const int row = quad*4 + r;
            short* prow = sPw + row*64 + l7;
            const int rx = (row & 7);
            float sum = 0.f;
            #pragma unroll
            for (int n = 0; n < 4; ++n) {
                float pv = __expf(s[n][r] - mn);
                sum += pv;
                prow[((n*2 + (l15 >> 3)) ^ rx) << 3] = f2bf(pv);
            }
            sum += __shfl_xor(sum, 1);
            sum += __shfl_xor(sum, 2);
            sum += __shfl_xor(sum, 4);
            sum += __shfl_xor(sum, 8);
            l_r[r] = l_r[r]*a + sum;
        }
        if (__any(need_rescale)) {
            #pragma unroll
            for (int n2 = 0; n2 < 16; ++n2)
                #pragma unroll
                for (int r = 0; r < 4; ++r) o[n2][r] *= alpha[r];
        }

        // ---- O += P * V^T (same-wave P, no barrier; swizzled frag reads) ----
        #pragma unroll
        for (int t2 = 0; t2 < 2; ++t2) {
            const int cx = (((t2*4 + quad) ^ l7) << 3);
            bf16x8 af = *(const bf16x8*)(sPw + l15*64 + cx);
            #pragma unroll
            for (int n2 = 0; n2 < 16; ++n2) {
                bf16x8 bfr = *(const bf16x8*)(sV + (n2*16 + l15)*64 + cx);
                o[n2] = __builtin_amdgcn_mfma_f32_16x16x32_bf16(af, bfr, o[n2], 0, 0, 0);
            }
        }
    }

    // epilogue: unnormalized O + (m,l) per row
    const size_t base = (size_t)split * NROWS;
    #pragma unroll
    for (int r = 0; r < 4; ++r) {
        int row = q0 + wave*16 + quad*4 + r;
        if (l15 == 0) { Mpart[base + row] = m_r[r]; Lpart[base + row] = l_r[r]; }
        float* orow = Opart + (base + row) * (size_t)DVDIM;
        #pragma unroll
        for (int n2 = 0; n2 < 16; ++n2)
            orow[n2*16 + l15] = o[r][0]*0.f + o[n2][r];   // plain o[n2][r]
    }
}

// ---------------------------------------------------------------------------
// Combine ns split partials: out = sum_s(Os*ws) / sum_s(ls*ws), ws=exp(ms-M).
// grid = NROWS/64 = 256 blocks, block = 256 (= DV); 64 rows per block.
// ---------------------------------------------------------------------------
__global__ void combine_splits(
    const float* __restrict__ Opart, const float* __restrict__ Mpart,
    const float* __restrict__ Lpart, float* __restrict__ out, int ns)
{
    const int r0 = blockIdx.x * 64;
    const int dv = threadIdx.x;
    for (int i = 0; i < 64; ++i) {
        const int row = r0 + i;
        float M = -1e30f;
        for (int s = 0; s < ns; ++s) M = fmaxf(M, Mpart[(size_t)s*NROWS + row]);
        float denom = 0.f, acc = 0.f;
        for (int s = 0; s < ns; ++s) {
            float w = __expf(Mpart[(size_t)s*NROWS + row] - M);
            denom += Lpart[(size_t)s*NROWS + row] * w;
            acc   += Opart[((size_t)s*NROWS + row)*DVDIM + dv] * w;
        }
        out[(size_t)row*DVDIM + dv] = acc / denom;
    }
}

extern "C" void kernel_launch(void* const* d_in, const int* in_sizes, int n_in,
                              void* d_out, int out_size, void* d_ws, size_t ws_size,
                              hipStream_t stream) {
    const float* X  = (const float*)d_in[0];   // [8,2048,512]
    const float* Y  = (const float*)d_in[1];   // [4096,512]
    const float* Z  = (const float*)d_in[2];   // [4096,512]
    const float* Wk = (const float*)d_in[3];   // [512,512]
    const float* Wv = (const float*)d_in[4];   // [256,512]
    float* out = (float*)d_out;

    // choose split count by workspace budget (needs 6MB + ns*(16MB+128KB))
    size_t need4 = (size_t)(6u<<20) + 4u*((16u<<20) + (size_t)NROWS*8);
    int ns = (ws_size >= need4) ? 4 : 2;
    int nj = (SKN/64) / ns;

    char* ws = (char*)d_ws;
    unsigned short* keyb = (unsigned short*)ws;                    // 4 MB, natural [4096][512]
    unsigned short* vtb  = (unsigned short*)(ws + (4u<<20));       // 2 MB, natural [256][4096]
    float* Opart = (float*)(ws + (6u<<20));                        // ns x 16 MB
    float* Mpart = (float*)(ws + (6u<<20) + (size_t)ns*NROWS*DVDIM*4);
    float* Lpart = Mpart + (size_t)ns*NROWS;

    // key[s][d] = sum_c Y[s][c] * Wk[d][c]
    gemm_nt_f32_bf16<<<dim3(SKN/64, DDIM/64), dim3(256), 0, stream>>>(
        Y, Wk, keyb, SKN, DDIM, DDIM);
    // vt[d][s] = sum_c Wv[d][c] * Z[s][c]   (value transposed)
    gemm_nt_f32_bf16<<<dim3(DVDIM/64, SKN/64), dim3(256), 0, stream>>>(
        Wv, Z, vtb, DVDIM, SKN, DDIM);
    // fused attention over ns SK-splits
    attn_fused<<<dim3(NROWS/64, ns), dim3(256), 0, stream>>>(
        X, keyb, vtb, Opart, Mpart, Lpart, nj);
    // merge splits
    combine_splits<<<dim3(NROWS/64), dim3(256), 0, stream>>>(Opart, Mpart, Lpart, out, ns);
}

// Round 5
// 343.988 us; speedup vs baseline: 1.4541x; 1.4541x over previous
//
#include <hip/hip_runtime.h>
#include <hip/hip_bf16.h>

// Problem constants
#define NB    8
#define SQN   2048
#define SKN   4096
#define DDIM  512
#define DVDIM 256
#define NROWS (NB*SQN)      // 16384

typedef __attribute__((ext_vector_type(8))) short bf16x8;   // 8 bf16 = 4 VGPRs (MFMA A/B frag)
typedef __attribute__((ext_vector_type(4))) short bf16x4;
typedef __attribute__((ext_vector_type(4))) float f32x4;    // MFMA C/D frag

// fp32 -> bf16 round-to-nearest-even, bit pattern as short
__device__ __forceinline__ short f2bf(float f) {
    unsigned u = __float_as_uint(f);
    return (short)((u + 0x7FFFu + ((u >> 16) & 1u)) >> 16);
}

// async global->LDS, 16B per lane; LDS dst = wave-uniform base + lane*16,
// global src may be per-lane (used for read-side swizzle)
__device__ __forceinline__ void gload_lds16(const void* g, void* l) {
    __builtin_amdgcn_global_load_lds(
        (const __attribute__((address_space(1))) unsigned int*)g,
        (__attribute__((address_space(3))) unsigned int*)l, 16, 0, 0);
}

// ---------------------------------------------------------------------------
// Generic NT GEMM: C[m][n] = sum_k A[m][k]*B[n][k], A:MxK f32, B:NxK f32,
// C natural row-major bf16. Tiles 64x64, block=256 (4 waves x 16 rows), Kc=128.
// grid = (M/64, N/64)
// ---------------------------------------------------------------------------
__global__ __launch_bounds__(256, 2) void gemm_nt_f32_bf16(
    const float* __restrict__ A, const float* __restrict__ Bm,
    unsigned short* __restrict__ C, int M, int N, int K)
{
    __shared__ short sA[64*128];   // 16 KB
    __shared__ short sB[64*128];   // 16 KB
    const int tid  = threadIdx.x;
    const int wave = tid >> 6;
    const int lane = tid & 63;
    const int quad = lane >> 4;
    const int l15  = lane & 15;
    const int m0 = blockIdx.x * 64;
    const int n0 = blockIdx.y * 64;

    f32x4 acc[4];
    #pragma unroll
    for (int n = 0; n < 4; ++n) { acc[n][0]=0.f; acc[n][1]=0.f; acc[n][2]=0.f; acc[n][3]=0.f; }

    for (int kc = 0; kc < K; kc += 128) {
        __syncthreads();
        #pragma unroll
        for (int it = 0; it < 8; ++it) {
            int f = it*1024 + tid*4;          // element index in 64x128 tile
            int row = f >> 7, col = f & 127;
            float4 av = *(const float4*)(A + (size_t)(m0+row)*K + kc + col);
            bf16x4 a4; a4[0]=f2bf(av.x); a4[1]=f2bf(av.y); a4[2]=f2bf(av.z); a4[3]=f2bf(av.w);
            *(bf16x4*)(sA + f) = a4;
            float4 bv = *(const float4*)(Bm + (size_t)(n0+row)*K + kc + col);
            bf16x4 b4; b4[0]=f2bf(bv.x); b4[1]=f2bf(bv.y); b4[2]=f2bf(bv.z); b4[3]=f2bf(bv.w);
            *(bf16x4*)(sB + f) = b4;
        }
        __syncthreads();
        #pragma unroll
        for (int t = 0; t < 4; ++t) {
            bf16x8 af = *(const bf16x8*)(sA + (wave*16 + l15)*128 + t*32 + quad*8);
            #pragma unroll
            for (int n = 0; n < 4; ++n) {
                bf16x8 bfr = *(const bf16x8*)(sB + (n*16 + l15)*128 + t*32 + quad*8);
                acc[n] = __builtin_amdgcn_mfma_f32_16x16x32_bf16(af, bfr, acc[n], 0, 0, 0);
            }
        }
    }
    #pragma unroll
    for (int n = 0; n < 4; ++n)
        #pragma unroll
        for (int r = 0; r < 4; ++r) {
            int m  = m0 + wave*16 + quad*4 + r;
            int nn = n0 + n*16 + l15;
            C[(size_t)m*N + nn] = (unsigned short)f2bf(acc[n][r]);
        }
}

// ---------------------------------------------------------------------------
// Fused attention: grid = (NROWS/64, nsplit), block = 256 (4 waves x 16 rows).
// LDS 40 KB: sK 16 (K chunks) + sV 16 (one 128-dv half of V^T) + sP 8.
// -> 4 blocks/CU at ~120 VGPR (launch_bounds(256,2): do NOT force higher —
//    bound 3 made the compiler spill to scratch in R4: 84 VGPR, 2x HBM, 1.6x slower).
// Per j: 4x(stage K_c; QK_c) with V-h0 staged at c==0; softmax+P->sP;
// PV over dv 0..127; barrier; stage V-h1; barrier; PV over dv 128..255.
// ---------------------------------------------------------------------------
__global__ __launch_bounds__(256, 2) void attn_fused(
    const float* __restrict__ X,            // [16384][512] fp32
    const unsigned short* __restrict__ Kb,  // key bf16 [4096][512] natural
    const unsigned short* __restrict__ Vt,  // V^T bf16 [256][4096] natural
    float* __restrict__ Opart,              // [nsplit][16384][256]
    float* __restrict__ Mpart,              // [nsplit][16384]
    float* __restrict__ Lpart,              // [nsplit][16384]
    int nj)                                 // key-blocks per split
{
    __shared__ short sK[8192];      // 16 KB: K chunk, 64 keys x 128 d (swizzled)
    __shared__ short sV[8192];      // 16 KB: V^T half, 128 dv x 64 keys (swizzled)
    __shared__ short sP[4096];      //  8 KB: P, 4 waves x 16 rows x 64 keys
    const int tid  = threadIdx.x;
    const int wave = tid >> 6;
    const int lane = tid & 63;
    const int quad = lane >> 4;
    const int l15  = lane & 15;
    const int l7   = lane & 7;
    const int split = blockIdx.y;
    const int q0   = blockIdx.x * 64;
    const int sb0  = split * nj;
    const float scale = 0.04419417382415922f;  // 1/sqrt(512)

    // Q fragments (scale folded): A[m=l15][k=quad*8+j], 16 k-steps (64 VGPRs)
    bf16x8 qf[16];
    {
        const float* xrow = X + (size_t)(q0 + wave*16 + l15) * DDIM;
        #pragma unroll
        for (int t = 0; t < 16; ++t) {
            float4 a = *(const float4*)(xrow + t*32 + quad*8);
            float4 b = *(const float4*)(xrow + t*32 + quad*8 + 4);
            bf16x8 q;
            q[0]=f2bf(a.x*scale); q[1]=f2bf(a.y*scale); q[2]=f2bf(a.z*scale); q[3]=f2bf(a.w*scale);
            q[4]=f2bf(b.x*scale); q[5]=f2bf(b.y*scale); q[6]=f2bf(b.z*scale); q[7]=f2bf(b.w*scale);
            qf[t] = q;
        }
    }

    f32x4 o[16];
    #pragma unroll
    for (int i = 0; i < 16; ++i) { o[i][0]=0.f; o[i][1]=0.f; o[i][2]=0.f; o[i][3]=0.f; }
    float m_r[4] = {-1e30f,-1e30f,-1e30f,-1e30f};
    float l_r[4] = {0.f,0.f,0.f,0.f};
    short* sPw = sP + wave*1024;    // 16 rows x 64 keys, wave-private

    const int wq = wave*4 + quad;   // K-stage dest row phase (= row & 15)
    // V-stage: dest dv_local = it*32 + wave*8 + (lane>>3); (dv_local&7)==lane>>3
    const int vrow = wave*8 + (lane>>3);
    const int vswz = (l7 ^ (lane>>3)) << 3;

    for (int j = 0; j < nj; ++j) {
        const int sk0 = (sb0 + j) * 64;
        f32x4 s[4];
        #pragma unroll
        for (int n = 0; n < 4; ++n) { s[n][0]=0.f; s[n][1]=0.f; s[n][2]=0.f; s[n][3]=0.f; }

        #pragma unroll
        for (int c = 0; c < 4; ++c) {
            __syncthreads();   // (A) prior consumers of sK (and sV at c==0) done
            if (c == 0) {
                // stage V^T half 0: dv 0..127
                const unsigned short* vsrc = Vt + sk0 + (size_t)vrow*SKN + vswz;
                char* vdst = (char*)sV + wave*1024;
                #pragma unroll
                for (int it = 0; it < 4; ++it)
                    gload_lds16(vsrc + (size_t)it*32*SKN, vdst + it*4096);
            }
            // stage K chunk 64x128: dest row = it*16+wq, slot l15 holds d-chunk l15^wq
            const unsigned short* ksrc = Kb + (size_t)(sk0 + wq)*DDIM
                + c*128 + ((l15 ^ wq) << 3);
            char* kdst = (char*)sK + wave*1024;
            #pragma unroll
            for (int it = 0; it < 4; ++it)
                gload_lds16(ksrc + (size_t)it*16*DDIM, kdst + it*4096);
            __syncthreads();   // (B) staged data visible
            #pragma unroll
            for (int t = 0; t < 4; ++t) {
                bf16x8 af = qf[c*4 + t];
                #pragma unroll
                for (int n = 0; n < 4; ++n) {
                    bf16x8 bfr = *(const bf16x8*)(sK + (n*16 + l15)*128
                                                  + (((t*4 + quad) ^ l15) << 3));
                    s[n] = __builtin_amdgcn_mfma_f32_16x16x32_bf16(af, bfr, s[n], 0, 0, 0);
                }
            }
        }

        // ---- online softmax (rows = quad*4+r), P written inline to sP ----
        float alpha[4];
        int need_rescale = 0;
        #pragma unroll
        for (int r = 0; r < 4; ++r) {
            float v = fmaxf(fmaxf(s[0][r], s[1][r]), fmaxf(s[2][r], s[3][r]));
            v = fmaxf(v, __shfl_xor(v, 1));
            v = fmaxf(v, __shfl_xor(v, 2));
            v = fmaxf(v, __shfl_xor(v, 4));
            v = fmaxf(v, __shfl_xor(v, 8));
            float mn = fmaxf(m_r[r], v);
            float a  = __expf(m_r[r] - mn);
            alpha[r] = a;
            need_rescale |= (a < 1.0f);
            m_r[r] = mn;
            const int row = quad*4 + r;
            short* prow = sPw + row*64 + l7;
            const int rx = row & 7;
            float sum = 0.f;
            #pragma unroll
            for (int n = 0; n < 4; ++n) {
                float pv = __expf(s[n][r] - mn);
                sum += pv;
                prow[((n*2 + (l15 >> 3)) ^ rx) << 3] = f2bf(pv);
            }
            sum += __shfl_xor(sum, 1);
            sum += __shfl_xor(sum, 2);
            sum += __shfl_xor(sum, 4);
            sum += __shfl_xor(sum, 8);
            l_r[r] = l_r[r]*a + sum;
        }
        if (__any(need_rescale)) {
            #pragma unroll
            for (int n2 = 0; n2 < 16; ++n2)
                #pragma unroll
                for (int r = 0; r < 4; ++r) o[n2][r] *= alpha[r];
        }

        // ---- PV half 0: dv 0..127 (same-wave P, no barrier needed) ----
        #pragma unroll
        for (int t2 = 0; t2 < 2; ++t2) {
            const int cx = (((t2*4 + quad) ^ l7) << 3);
            bf16x8 af = *(const bf16x8*)(sPw + l15*64 + cx);
            #pragma unroll
            for (int n2 = 0; n2 < 8; ++n2) {
                bf16x8 bfr = *(const bf16x8*)(sV + (n2*16 + l15)*64 + cx);
                o[n2] = __builtin_amdgcn_mfma_f32_16x16x32_bf16(af, bfr, o[n2], 0, 0, 0);
            }
        }
        __syncthreads();   // (C) all waves done reading V half 0
        {
            // stage V^T half 1: dv 128..255
            const unsigned short* vsrc = Vt + sk0 + (size_t)(128 + vrow)*SKN + vswz;
            char* vdst = (char*)sV + wave*1024;
            #pragma unroll
            for (int it = 0; it < 4; ++it)
                gload_lds16(vsrc + (size_t)it*32*SKN, vdst + it*4096);
        }
        __syncthreads();   // (D) half 1 visible
        // ---- PV half 1: dv 128..255 ----
        #pragma unroll
        for (int t2 = 0; t2 < 2; ++t2) {
            const int cx = (((t2*4 + quad) ^ l7) << 3);
            bf16x8 af = *(const bf16x8*)(sPw + l15*64 + cx);
            #pragma unroll
            for (int n2 = 0; n2 < 8; ++n2) {
                bf16x8 bfr = *(const bf16x8*)(sV + (n2*16 + l15)*64 + cx);
                o[8 + n2] = __builtin_amdgcn_mfma_f32_16x16x32_bf16(af, bfr, o[8 + n2], 0, 0, 0);
            }
        }
    }

    // epilogue: unnormalized O + (m,l) per row
    const size_t base = (size_t)split * NROWS;
    #pragma unroll
    for (int r = 0; r < 4; ++r) {
        int row = q0 + wave*16 + quad*4 + r;
        if (l15 == 0) { Mpart[base + row] = m_r[r]; Lpart[base + row] = l_r[r]; }
        float* orow = Opart + (base + row) * (size_t)DVDIM;
        #pragma unroll
        for (int n2 = 0; n2 < 16; ++n2)
            orow[n2*16 + l15] = o[n2][r];
    }
}

// ---------------------------------------------------------------------------
// Combine ns split partials: out = sum_s(Os*ws) / sum_s(ls*ws), ws=exp(ms-M).
// grid = NROWS/4, block = 256: 4 rows/block, each thread one float4 of a row.
// Fully coalesced (64 lanes x 16 B = 1 KB per wave access).
// ---------------------------------------------------------------------------
__global__ void combine_splits(
    const float* __restrict__ Opart, const float* __restrict__ Mpart,
    const float* __restrict__ Lpart, float* __restrict__ out, int ns)
{
    const int row = blockIdx.x * 4 + (threadIdx.x >> 6);
    const int dv4 = (threadIdx.x & 63) * 4;
    float M = -1e30f;
    for (int s = 0; s < ns; ++s) M = fmaxf(M, Mpart[(size_t)s*NROWS + row]);
    float denom = 0.f;
    float4 acc = make_float4(0.f, 0.f, 0.f, 0.f);
    for (int s = 0; s < ns; ++s) {
        float w = __expf(Mpart[(size_t)s*NROWS + row] - M);
        denom += Lpart[(size_t)s*NROWS + row] * w;
        float4 ov = *(const float4*)(Opart + ((size_t)s*NROWS + row)*DVDIM + dv4);
        acc.x += ov.x*w; acc.y += ov.y*w; acc.z += ov.z*w; acc.w += ov.w*w;
    }
    float inv = 1.0f / denom;
    float4 res = make_float4(acc.x*inv, acc.y*inv, acc.z*inv, acc.w*inv);
    *(float4*)(out + (size_t)row*DVDIM + dv4) = res;
}

extern "C" void kernel_launch(void* const* d_in, const int* in_sizes, int n_in,
                              void* d_out, int out_size, void* d_ws, size_t ws_size,
                              hipStream_t stream) {
    const float* X  = (const float*)d_in[0];   // [8,2048,512]
    const float* Y  = (const float*)d_in[1];   // [4096,512]
    const float* Z  = (const float*)d_in[2];   // [4096,512]
    const float* Wk = (const float*)d_in[3];   // [512,512]
    const float* Wv = (const float*)d_in[4];   // [256,512]
    float* out = (float*)d_out;

    // choose split count by workspace budget (needs 6MB + ns*(16MB+128KB))
    size_t need4 = (size_t)(6u<<20) + 4u*((16u<<20) + (size_t)NROWS*8);
    int ns = (ws_size >= need4) ? 4 : 2;
    int nj = (SKN/64) / ns;

    char* ws = (char*)d_ws;
    unsigned short* keyb = (unsigned short*)ws;                    // 4 MB, natural [4096][512]
    unsigned short* vtb  = (unsigned short*)(ws + (4u<<20));       // 2 MB, natural [256][4096]
    float* Opart = (float*)(ws + (6u<<20));                        // ns x 16 MB
    float* Mpart = (float*)(ws + (6u<<20) + (size_t)ns*NROWS*DVDIM*4);
    float* Lpart = Mpart + (size_t)ns*NROWS;

    // key[s][d] = sum_c Y[s][c] * Wk[d][c]
    gemm_nt_f32_bf16<<<dim3(SKN/64, DDIM/64), dim3(256), 0, stream>>>(
        Y, Wk, keyb, SKN, DDIM, DDIM);
    // vt[d][s] = sum_c Wv[d][c] * Z[s][c]   (value transposed)
    gemm_nt_f32_bf16<<<dim3(DVDIM/64, SKN/64), dim3(256), 0, stream>>>(
        Wv, Z, vtb, DVDIM, SKN, DDIM);
    // fused attention over ns SK-splits
    attn_fused<<<dim3(NROWS/64, ns), dim3(256), 0, stream>>>(
        X, keyb, vtb, Opart, Mpart, Lpart, nj);
    // merge splits
    combine_splits<<<dim3(NROWS/4), dim3(256), 0, stream>>>(Opart, Mpart, Lpart, out, ns);
}

// Round 6
// 299.351 us; speedup vs baseline: 1.6709x; 1.1491x over previous
//
#include <hip/hip_runtime.h>
#include <hip/hip_bf16.h>

// Problem constants
#define NB    8
#define SQN   2048
#define SKN   4096
#define DDIM  512
#define DVDIM 256
#define NROWS (NB*SQN)      // 16384
#define NS    2             // SK splits
#define NJ    ((SKN/64)/NS) // 32 j-iterations per split

typedef __attribute__((ext_vector_type(8))) short bf16x8;   // 8 bf16 = 4 VGPRs (MFMA A/B frag)
typedef __attribute__((ext_vector_type(4))) short bf16x4;
typedef __attribute__((ext_vector_type(4))) float f32x4;    // MFMA C/D frag

// fp32 -> bf16 round-to-nearest-even, bit pattern as short
__device__ __forceinline__ short f2bf(float f) {
    unsigned u = __float_as_uint(f);
    return (short)((u + 0x7FFFu + ((u >> 16) & 1u)) >> 16);
}

// async global->LDS, 16B per lane; LDS dst = wave-uniform base + lane*16,
// global src may be per-lane (used for read-side swizzle)
__device__ __forceinline__ void gload_lds16(const void* g, void* l) {
    __builtin_amdgcn_global_load_lds(
        (const __attribute__((address_space(1))) unsigned int*)g,
        (__attribute__((address_space(3))) unsigned int*)l, 16, 0, 0);
}

// ---------------------------------------------------------------------------
// Fused projection GEMMs, one launch (R5 post-mortem: ~125us of non-attn time
// looks like per-launch overhead -> cut a launch). grid = (64, 8, 2).
//  z=0: key[s][d]  = sum_c Y[s][c]*Wk[d][c]   M=4096 N=512
//  z=1: vt[dv][s]  = sum_c Wv[dv][c]*Z[s][c]  M=256  N=4096 (uses 256 of 512 tiles)
// NT GEMM, 64x64 tiles, Kc=128, staging double-buffered through registers
// (prefetch kc+1 while MFMAing kc — hides HBM latency).
// ---------------------------------------------------------------------------
__global__ __launch_bounds__(256, 2) void proj_gemms(
    const float* __restrict__ Y, const float* __restrict__ Z,
    const float* __restrict__ Wk, const float* __restrict__ Wv,
    unsigned short* __restrict__ keyb, unsigned short* __restrict__ vtb)
{
    __shared__ short sA[64*128];   // 16 KB
    __shared__ short sB[64*128];   // 16 KB
    const float *A, *Bm;
    unsigned short* C;
    int N, m0, n0;
    if (blockIdx.z == 0) {
        A = Y; Bm = Wk; C = keyb; N = DDIM;
        m0 = blockIdx.x * 64; n0 = blockIdx.y * 64;
    } else {
        int lin = blockIdx.x * 8 + blockIdx.y;
        if (lin >= 256) return;                 // value GEMM needs 256 tiles
        A = Wv; Bm = Z; C = vtb; N = SKN;
        m0 = (lin >> 6) * 64; n0 = (lin & 63) * 64;
    }
    const int tid  = threadIdx.x;
    const int wave = tid >> 6;
    const int lane = tid & 63;
    const int quad = lane >> 4;
    const int l15  = lane & 15;

    f32x4 acc[4];
    #pragma unroll
    for (int n = 0; n < 4; ++n) { acc[n][0]=0.f; acc[n][1]=0.f; acc[n][2]=0.f; acc[n][3]=0.f; }

    float4 ra[8], rb[8];
    #pragma unroll
    for (int it = 0; it < 8; ++it) {            // prefetch kc=0
        int f = it*1024 + tid*4, row = f >> 7, col = f & 127;
        ra[it] = *(const float4*)(A  + (size_t)(m0+row)*DDIM + col);
        rb[it] = *(const float4*)(Bm + (size_t)(n0+row)*DDIM + col);
    }

    for (int kc = 0; kc < DDIM; kc += 128) {
        __syncthreads();                        // LDS free (prev MFMA done)
        #pragma unroll
        for (int it = 0; it < 8; ++it) {
            int f = it*1024 + tid*4;
            bf16x4 a4; a4[0]=f2bf(ra[it].x); a4[1]=f2bf(ra[it].y); a4[2]=f2bf(ra[it].z); a4[3]=f2bf(ra[it].w);
            *(bf16x4*)(sA + f) = a4;
            bf16x4 b4; b4[0]=f2bf(rb[it].x); b4[1]=f2bf(rb[it].y); b4[2]=f2bf(rb[it].z); b4[3]=f2bf(rb[it].w);
            *(bf16x4*)(sB + f) = b4;
        }
        __syncthreads();                        // staged visible
        if (kc + 128 < DDIM) {                  // prefetch kc+1 (in flight under MFMA)
            #pragma unroll
            for (int it = 0; it < 8; ++it) {
                int f = it*1024 + tid*4, row = f >> 7, col = f & 127;
                ra[it] = *(const float4*)(A  + (size_t)(m0+row)*DDIM + kc + 128 + col);
                rb[it] = *(const float4*)(Bm + (size_t)(n0+row)*DDIM + kc + 128 + col);
            }
        }
        #pragma unroll
        for (int t = 0; t < 4; ++t) {
            bf16x8 af = *(const bf16x8*)(sA + (wave*16 + l15)*128 + t*32 + quad*8);
            #pragma unroll
            for (int n = 0; n < 4; ++n) {
                bf16x8 bfr = *(const bf16x8*)(sB + (n*16 + l15)*128 + t*32 + quad*8);
                acc[n] = __builtin_amdgcn_mfma_f32_16x16x32_bf16(af, bfr, acc[n], 0, 0, 0);
            }
        }
    }
    #pragma unroll
    for (int n = 0; n < 4; ++n)
        #pragma unroll
        for (int r = 0; r < 4; ++r) {
            int m  = m0 + wave*16 + quad*4 + r;
            int nn = n0 + n*16 + l15;
            C[(size_t)m*N + nn] = (unsigned short)f2bf(acc[n][r]);
        }
}

// ---------------------------------------------------------------------------
// Fused attention: grid = (NROWS/64, NS), block = 256 (4 waves x 16 Q-rows).
// Software-pipelined K-loop (R5 lesson: every stage must have a compute phase
// between issue and its barrier-drain):
//   per c-phase: barrier -> issue K(c+1) into other sK buffer -> QK(c).
//   V(j) issued at c==0 (drained by c==1 barrier, consumed at PV).
//   K(j+1,0) issued at c==3 (drained at next j's c==0, after softmax+PV).
// 4 barriers/j, zero exposed drains. LDS 72 KB -> 2 blocks/CU.
// launch_bounds(256,2) ONLY — forcing 3 made the regalloc spill (R4: 2x HBM).
// ---------------------------------------------------------------------------
__global__ __launch_bounds__(256, 2) void attn_fused(
    const float* __restrict__ X,            // [16384][512] fp32
    const unsigned short* __restrict__ Kb,  // key bf16 [4096][512] natural
    const unsigned short* __restrict__ Vt,  // V^T bf16 [256][4096] natural
    float* __restrict__ Opart,              // [NS][16384][256]
    float* __restrict__ Mpart,              // [NS][16384]
    float* __restrict__ Lpart)              // [NS][16384]
{
    __shared__ short sK[2][8192];   // 2 x 16 KB: K chunk dbuf (64 keys x 128 d, swizzled)
    __shared__ short sV[16384];     // 32 KB: V^T 256 dv x 64 keys (swizzled)
    __shared__ short sP[4096];      //  8 KB: P, 4 waves x 16 rows x 64 keys (wave-private)
    const int tid  = threadIdx.x;
    const int wave = tid >> 6;
    const int lane = tid & 63;
    const int quad = lane >> 4;
    const int l15  = lane & 15;
    const int l7   = lane & 7;
    const int split = blockIdx.y;
    const int q0   = blockIdx.x * 64;
    const int sb0  = split * NJ;
    const float scale = 0.04419417382415922f;  // 1/sqrt(512)

    // Q fragments (scale folded): A[m=l15][k=quad*8+j], 16 k-steps (64 VGPRs)
    bf16x8 qf[16];
    {
        const float* xrow = X + (size_t)(q0 + wave*16 + l15) * DDIM;
        #pragma unroll
        for (int t = 0; t < 16; ++t) {
            float4 a = *(const float4*)(xrow + t*32 + quad*8);
            float4 b = *(const float4*)(xrow + t*32 + quad*8 + 4);
            bf16x8 q;
            q[0]=f2bf(a.x*scale); q[1]=f2bf(a.y*scale); q[2]=f2bf(a.z*scale); q[3]=f2bf(a.w*scale);
            q[4]=f2bf(b.x*scale); q[5]=f2bf(b.y*scale); q[6]=f2bf(b.z*scale); q[7]=f2bf(b.w*scale);
            qf[t] = q;
        }
    }

    f32x4 o[16];
    #pragma unroll
    for (int i = 0; i < 16; ++i) { o[i][0]=0.f; o[i][1]=0.f; o[i][2]=0.f; o[i][3]=0.f; }
    float m_r[4] = {-1e30f,-1e30f,-1e30f,-1e30f};
    float l_r[4] = {0.f,0.f,0.f,0.f};
    short* sPw = sP + wave*1024;    // 16 rows x 64 keys, wave-private

    // read-side swizzle constants (verified conflict-free in R5: SQ_LDS_BANK_CONFLICT=0)
    const int wq   = wave*4 + quad;          // K-stage dest row phase (= row & 15)
    const int vrow = wave*8 + (lane>>3);     // V-stage dest dv phase
    const int vswz = (l7 ^ (lane>>3)) << 3;

    // issue K chunk c of key-block sk0 into buffer buf
    #define STAGE_K(sk0_, c_, buf_)                                            \
        do {                                                                   \
            const unsigned short* ksrc_ = Kb + (size_t)((sk0_) + wq)*DDIM      \
                + (c_)*128 + ((l15 ^ wq) << 3);                                \
            char* kdst_ = (char*)(buf_) + wave*1024;                           \
            _Pragma("unroll")                                                  \
            for (int it_ = 0; it_ < 4; ++it_)                                  \
                gload_lds16(ksrc_ + (size_t)it_*16*DDIM, kdst_ + it_*4096);    \
        } while (0)

    // prologue: K(0,0) into sK[0] (drained by first c==0 barrier)
    STAGE_K(sb0*64, 0, sK[0]);

    for (int j = 0; j < NJ; ++j) {
        const int sk0 = (sb0 + j) * 64;
        f32x4 s[4];
        #pragma unroll
        for (int n = 0; n < 4; ++n) { s[n][0]=0.f; s[n][1]=0.f; s[n][2]=0.f; s[n][3]=0.f; }

        #pragma unroll
        for (int c = 0; c < 4; ++c) {
            __syncthreads();   // frees other sK buffer + drains chunk c (+V at c==1)
            if (c == 0) {
                // issue V(j): consumed at PV, drained by c==1 barrier
                const unsigned short* vsrc = Vt + sk0 + (size_t)vrow*SKN + vswz;
                char* vdst = (char*)sV + wave*1024;
                #pragma unroll
                for (int it = 0; it < 8; ++it)
                    gload_lds16(vsrc + (size_t)it*32*SKN, vdst + it*4096);
            }
            // issue next K chunk into the other buffer (drain overlapped w/ QK below)
            if (c < 3)            STAGE_K(sk0,      c + 1, sK[(c + 1) & 1]);
            else if (j + 1 < NJ)  STAGE_K(sk0 + 64, 0,     sK[0]);
            // QK on chunk c (staged one phase ago, drained by this phase's barrier)
            const short* sKc = sK[c & 1];
            #pragma unroll
            for (int t = 0; t < 4; ++t) {
                bf16x8 af = qf[c*4 + t];
                #pragma unroll
                for (int n = 0; n < 4; ++n) {
                    bf16x8 bfr = *(const bf16x8*)(sKc + (n*16 + l15)*128
                                                  + (((t*4 + quad) ^ l15) << 3));
                    s[n] = __builtin_amdgcn_mfma_f32_16x16x32_bf16(af, bfr, s[n], 0, 0, 0);
                }
            }
        }

        // ---- online softmax (rows = quad*4+r), P written inline to sP ----
        float alpha[4];
        int need_rescale = 0;
        #pragma unroll
        for (int r = 0; r < 4; ++r) {
            float v = fmaxf(fmaxf(s[0][r], s[1][r]), fmaxf(s[2][r], s[3][r]));
            v = fmaxf(v, __shfl_xor(v, 1));
            v = fmaxf(v, __shfl_xor(v, 2));
            v = fmaxf(v, __shfl_xor(v, 4));
            v = fmaxf(v, __shfl_xor(v, 8));
            float mn = fmaxf(m_r[r], v);
            float a  = __expf(m_r[r] - mn);
            alpha[r] = a;
            need_rescale |= (a < 1.0f);
            m_r[r] = mn;
            const int row = quad*4 + r;
            short* prow = sPw + row*64 + l7;
            const int rx = row & 7;
            float sum = 0.f;
            #pragma unroll
            for (int n = 0; n < 4; ++n) {
                float pv = __expf(s[n][r] - mn);
                sum += pv;
                prow[((n*2 + (l15 >> 3)) ^ rx) << 3] = f2bf(pv);
            }
            sum += __shfl_xor(sum, 1);
            sum += __shfl_xor(sum, 2);
            sum += __shfl_xor(sum, 4);
            sum += __shfl_xor(sum, 8);
            l_r[r] = l_r[r]*a + sum;
        }
        if (__any(need_rescale)) {
            #pragma unroll
            for (int n2 = 0; n2 < 16; ++n2)
                #pragma unroll
                for (int r = 0; r < 4; ++r) o[n2][r] *= alpha[r];
        }

        // ---- PV: O += P * V^T (same-wave P; V drained long ago; no barrier) ----
        #pragma unroll
        for (int t2 = 0; t2 < 2; ++t2) {
            const int cx = (((t2*4 + quad) ^ l7) << 3);
            bf16x8 af = *(const bf16x8*)(sPw + l15*64 + cx);
            #pragma unroll
            for (int n2 = 0; n2 < 16; ++n2) {
                bf16x8 bfr = *(const bf16x8*)(sV + (n2*16 + l15)*64 + cx);
                o[n2] = __builtin_amdgcn_mfma_f32_16x16x32_bf16(af, bfr, o[n2], 0, 0, 0);
            }
        }
    }
    #undef STAGE_K

    // epilogue: unnormalized O + (m,l) per row
    const size_t base = (size_t)split * NROWS;
    #pragma unroll
    for (int r = 0; r < 4; ++r) {
        int row = q0 + wave*16 + quad*4 + r;
        if (l15 == 0) { Mpart[base + row] = m_r[r]; Lpart[base + row] = l_r[r]; }
        float* orow = Opart + (base + row) * (size_t)DVDIM;
        #pragma unroll
        for (int n2 = 0; n2 < 16; ++n2)
            orow[n2*16 + l15] = o[n2][r];
    }
}

// ---------------------------------------------------------------------------
// Combine NS split partials: out = sum_s(Os*ws) / sum_s(ls*ws), ws=exp(ms-M).
// grid = NROWS/4, block = 256: 4 rows/block, one float4 per thread. Coalesced.
// ---------------------------------------------------------------------------
__global__ void combine_splits(
    const float* __restrict__ Opart, const float* __restrict__ Mpart,
    const float* __restrict__ Lpart, float* __restrict__ out)
{
    const int row = blockIdx.x * 4 + (threadIdx.x >> 6);
    const int dv4 = (threadIdx.x & 63) * 4;
    float M = -1e30f;
    #pragma unroll
    for (int s = 0; s < NS; ++s) M = fmaxf(M, Mpart[(size_t)s*NROWS + row]);
    float denom = 0.f;
    float4 acc = make_float4(0.f, 0.f, 0.f, 0.f);
    #pragma unroll
    for (int s = 0; s < NS; ++s) {
        float w = __expf(Mpart[(size_t)s*NROWS + row] - M);
        denom += Lpart[(size_t)s*NROWS + row] * w;
        float4 ov = *(const float4*)(Opart + ((size_t)s*NROWS + row)*DVDIM + dv4);
        acc.x += ov.x*w; acc.y += ov.y*w; acc.z += ov.z*w; acc.w += ov.w*w;
    }
    float inv = 1.0f / denom;
    *(float4*)(out + (size_t)row*DVDIM + dv4)
        = make_float4(acc.x*inv, acc.y*inv, acc.z*inv, acc.w*inv);
}

extern "C" void kernel_launch(void* const* d_in, const int* in_sizes, int n_in,
                              void* d_out, int out_size, void* d_ws, size_t ws_size,
                              hipStream_t stream) {
    const float* X  = (const float*)d_in[0];   // [8,2048,512]
    const float* Y  = (const float*)d_in[1];   // [4096,512]
    const float* Z  = (const float*)d_in[2];   // [4096,512]
    const float* Wk = (const float*)d_in[3];   // [512,512]
    const float* Wv = (const float*)d_in[4];   // [256,512]
    float* out = (float*)d_out;

    // workspace layout (~38.3 MB)
    char* ws = (char*)d_ws;
    unsigned short* keyb = (unsigned short*)ws;                    // 4 MB, natural [4096][512]
    unsigned short* vtb  = (unsigned short*)(ws + (4u<<20));       // 2 MB, natural [256][4096]
    float* Opart = (float*)(ws + (6u<<20));                        // NS x 16 MB
    float* Mpart = (float*)(ws + (6u<<20) + (size_t)NS*NROWS*DVDIM*4);
    float* Lpart = Mpart + (size_t)NS*NROWS;

    // both projections, one launch
    proj_gemms<<<dim3(64, 8, 2), dim3(256), 0, stream>>>(Y, Z, Wk, Wv, keyb, vtb);
    // fused attention over NS SK-splits
    attn_fused<<<dim3(NROWS/64, NS), dim3(256), 0, stream>>>(
        X, keyb, vtb, Opart, Mpart, Lpart);
    // merge splits
    combine_splits<<<dim3(NROWS/4), dim3(256), 0, stream>>>(Opart, Mpart, Lpart, out);
}